// Round 1
// baseline (816.502 us; speedup 1.0000x reference)
//
#include <hip/hip_runtime.h>
#include <math.h>

// MoE SwiGLU gather: out[t,k,:] = (silu(x[t]·W1[e]^T) * (x[t]·W3[e]^T)) · W2[e],
// e = expert_indices[t,k].  T=512 TOPK=2 E=8 H=2816 D=1024, fp32.
// R1: correct fp32 baseline. Grouped-by-expert GEMMs, LDS-tiled, no MFMA yet.

#define T_TOK 512
#define TOPK 2
#define NEXP 8
#define HDIM 2816
#define DDIM 1024
#define NPAIR (T_TOK * TOPK)   // 1024

#define KC 32          // k-chunk staged per iteration
#define HT 128         // h-tile per block (phase 1)
#define DT 128         // d-tile per block (phase 2)
#define MT 16          // m-tile (tokens) per block
#define WPAD 130       // padded leading dim for transposed W tiles (bank-conflict-free)

// -------- workspace layout (bytes) --------
// 0        : int counts[NEXP]
// 1024     : int lists[NEXP][NPAIR]
// 65536    : float hbuf[NPAIR][HDIM]   (~11.5 MB)

__global__ void route_kernel(const int* __restrict__ idx,
                             int* __restrict__ counts,
                             int* __restrict__ lists) {
    int p = threadIdx.x;          // one block, NPAIR threads
    if (p < NEXP) counts[p] = 0;  // ws is poisoned 0xAA every call: re-zero here
    __syncthreads();
    int e = idx[p];
    int pos = atomicAdd(&counts[e], 1);
    lists[e * NPAIR + pos] = p;
}

// Phase 1: hbuf[p, h] = silu(x[t]·w1[e,h,:]) * (x[t]·w3[e,h,:])
// grid (NEXP, HDIM/HT=22, NPAIR/MT=64), block 256.
__global__ void h_kernel(const float* __restrict__ x,
                         const float* __restrict__ w1,
                         const float* __restrict__ w3,
                         const int* __restrict__ counts,
                         const int* __restrict__ lists,
                         float* __restrict__ hbuf) {
    const int e = blockIdx.x;
    const int cnt = counts[e];
    const int m0 = blockIdx.z * MT;
    if (m0 >= cnt) return;
    const int h0 = blockIdx.y * HT;

    __shared__ float sW1[KC][WPAD];
    __shared__ float sW3[KC][WPAD];
    __shared__ float sX[MT][KC];
    __shared__ int sPair[MT];
    __shared__ int sTok[MT];

    const int tid = threadIdx.x;
    if (tid < MT) {
        int m = m0 + tid;
        int p = lists[e * NPAIR + ((m < cnt) ? m : (cnt - 1))];
        sPair[tid] = (m < cnt) ? p : -1;
        sTok[tid] = p / TOPK;
    }
    __syncthreads();

    const int hh = tid & 63;   // h within tile (plus +64 twin)
    const int mg = tid >> 6;   // 0..3, 4 tokens each

    float acc1[2][4] = {{0,0,0,0},{0,0,0,0}};
    float acc3[2][4] = {{0,0,0,0},{0,0,0,0}};

    const float* w1e = w1 + (size_t)e * HDIM * DDIM + (size_t)h0 * DDIM;
    const float* w3e = w3 + (size_t)e * HDIM * DDIM + (size_t)h0 * DDIM;

    for (int k0 = 0; k0 < DDIM; k0 += KC) {
        // stage W1/W3: HT(128) rows x KC(32) k, transposed -> sW[k][h].
        // 1024 float4 per matrix; 8 lanes cover one row's 32 floats (128B contig).
        #pragma unroll
        for (int pass = 0; pass < 4; ++pass) {
            int ii = tid + pass * 256;      // 0..1023
            int row = ii >> 3;              // 0..127
            int c4  = ii & 7;
            float4 a = *(const float4*)(w1e + (size_t)row * DDIM + k0 + c4 * 4);
            float4 b = *(const float4*)(w3e + (size_t)row * DDIM + k0 + c4 * 4);
            int kk = c4 * 4;
            sW1[kk+0][row] = a.x; sW1[kk+1][row] = a.y;
            sW1[kk+2][row] = a.z; sW1[kk+3][row] = a.w;
            sW3[kk+0][row] = b.x; sW3[kk+1][row] = b.y;
            sW3[kk+2][row] = b.z; sW3[kk+3][row] = b.w;
        }
        // stage X: MT x KC (512 floats, 2 per thread)
        #pragma unroll
        for (int r = 0; r < 2; ++r) {
            int ii = tid + r * 256;
            int m = ii >> 5;        // /KC
            int kk = ii & (KC - 1);
            sX[m][kk] = x[(size_t)sTok[m] * DDIM + k0 + kk];
        }
        __syncthreads();

        #pragma unroll
        for (int kk = 0; kk < KC; ++kk) {
            float v1a = sW1[kk][hh], v1b = sW1[kk][hh + 64];
            float v3a = sW3[kk][hh], v3b = sW3[kk][hh + 64];
            #pragma unroll
            for (int j = 0; j < 4; ++j) {
                float xv = sX[mg * 4 + j][kk];
                acc1[0][j] += v1a * xv;
                acc1[1][j] += v1b * xv;
                acc3[0][j] += v3a * xv;
                acc3[1][j] += v3b * xv;
            }
        }
        __syncthreads();
    }

    #pragma unroll
    for (int j = 0; j < 4; ++j) {
        int p = sPair[mg * 4 + j];
        if (p >= 0) {
            #pragma unroll
            for (int u = 0; u < 2; ++u) {
                float a = acc1[u][j];
                float s = a / (1.0f + __expf(-a));   // silu
                hbuf[(size_t)p * HDIM + h0 + u * 64 + hh] = s * acc3[u][j];
            }
        }
    }
}

// Phase 2: out[p, d] = sum_h hbuf[p,h] * w2[e,h,d]
// grid (NEXP, DDIM/DT=8, NPAIR/MT=64), block 256.
__global__ void out_kernel(const float* __restrict__ w2,
                           const int* __restrict__ counts,
                           const int* __restrict__ lists,
                           const float* __restrict__ hbuf,
                           float* __restrict__ out) {
    const int e = blockIdx.x;
    const int cnt = counts[e];
    const int m0 = blockIdx.z * MT;
    if (m0 >= cnt) return;
    const int d0 = blockIdx.y * DT;

    __shared__ float sB[KC][DT];     // w2 tile, direct copy (k-major already)
    __shared__ float sA[MT][KC];
    __shared__ int sPair[MT];

    const int tid = threadIdx.x;
    if (tid < MT) {
        int m = m0 + tid;
        sPair[tid] = (m < cnt) ? lists[e * NPAIR + m] : -1;
    }
    __syncthreads();

    const int dd = tid & 63;
    const int mg = tid >> 6;

    float acc[2][4] = {{0,0,0,0},{0,0,0,0}};
    const float* w2e = w2 + (size_t)e * HDIM * DDIM + d0;

    for (int k0 = 0; k0 < HDIM; k0 += KC) {
        // stage B: KC(32) rows x DT(128) cols = 4096 floats, float4 per thread x4
        #pragma unroll
        for (int pass = 0; pass < 4; ++pass) {
            int ii = tid + pass * 256;       // float4 index, 0..1023
            int row = ii >> 5;               // /(DT/4=32) -> 0..31
            int c4  = ii & 31;
            float4 v = *(const float4*)(w2e + (size_t)(k0 + row) * DDIM + c4 * 4);
            *(float4*)&sB[row][c4 * 4] = v;
        }
        // stage A: MT x KC
        #pragma unroll
        for (int r = 0; r < 2; ++r) {
            int ii = tid + r * 256;
            int m = ii >> 5;
            int kk = ii & (KC - 1);
            int p = sPair[m];
            sA[m][kk] = (p >= 0) ? hbuf[(size_t)p * HDIM + k0 + kk] : 0.0f;
        }
        __syncthreads();

        #pragma unroll
        for (int kk = 0; kk < KC; ++kk) {
            float bva = sB[kk][dd], bvb = sB[kk][dd + 64];
            #pragma unroll
            for (int j = 0; j < 4; ++j) {
                float av = sA[mg * 4 + j][kk];
                acc[0][j] += bva * av;
                acc[1][j] += bvb * av;
            }
        }
        __syncthreads();
    }

    #pragma unroll
    for (int j = 0; j < 4; ++j) {
        int p = sPair[mg * 4 + j];
        if (p >= 0) {
            #pragma unroll
            for (int u = 0; u < 2; ++u)
                out[(size_t)p * DDIM + d0 + u * 64 + dd] = acc[u][j];
        }
    }
}

extern "C" void kernel_launch(void* const* d_in, const int* in_sizes, int n_in,
                              void* d_out, int out_size, void* d_ws, size_t ws_size,
                              hipStream_t stream) {
    const float* x   = (const float*)d_in[0];
    const int*   idx = (const int*)d_in[1];
    const float* w1  = (const float*)d_in[2];
    const float* w2  = (const float*)d_in[3];
    const float* w3  = (const float*)d_in[4];
    float* out = (float*)d_out;

    char* ws = (char*)d_ws;
    int*   counts = (int*)ws;
    int*   lists  = (int*)(ws + 1024);
    float* hbuf   = (float*)(ws + 65536);

    route_kernel<<<1, NPAIR, 0, stream>>>(idx, counts, lists);
    h_kernel<<<dim3(NEXP, HDIM / HT, NPAIR / MT), 256, 0, stream>>>(
        x, w1, w3, counts, lists, hbuf);
    out_kernel<<<dim3(NEXP, DDIM / DT, NPAIR / MT), 256, 0, stream>>>(
        w2, counts, lists, hbuf, out);
}

// Round 2
// 325.331 us; speedup vs baseline: 2.5098x; 2.5098x over previous
//
#include <hip/hip_runtime.h>

// MoE SwiGLU gather, bf16-MFMA grouped-GEMM version.
// out[t,k,:] = (silu(x[t]·W1[e]^T) * (x[t]·W3[e]^T)) · W2[e],  e = idx[t,k]
// T=512 TOPK=2 E=8 H=2816 D=1024. Inputs fp32; compute via bf16 MFMA
// (fp32 has no MFMA on CDNA4: 113us VALU floor vs ~46us HBM floor).

#define NEXP 8
#define HDIM 2816
#define DDIM 1024
#define NPAIR 1024

typedef unsigned int uint;
typedef unsigned short ushort;
typedef __attribute__((ext_vector_type(8))) short bf16x8;   // 8 bf16 = 4 VGPRs
typedef __attribute__((ext_vector_type(4))) float fvec4;
typedef __attribute__((ext_vector_type(4))) uint uvec4;
typedef __attribute__((ext_vector_type(2))) uint uvec2;

__device__ __forceinline__ ushort f2bf(float f) {
    uint u = __builtin_bit_cast(uint, f);
    u += 0x7fff + ((u >> 16) & 1);          // RTNE
    return (ushort)(u >> 16);
}
__device__ __forceinline__ uint pack2(float lo, float hi) {
    return (uint)f2bf(lo) | ((uint)f2bf(hi) << 16);
}

// ---- workspace: [0] counts (32B) | [1024] lists 32KB | [65536] hbuf bf16 5.77MB
__global__ void route_kernel(const int* __restrict__ idx,
                             int* __restrict__ counts,
                             int* __restrict__ lists) {
    int p = threadIdx.x;
    if (p < NEXP) counts[p] = 0;     // ws re-poisoned every call: re-zero
    __syncthreads();
    int e = idx[p];
    int pos = atomicAdd(&counts[e], 1);
    lists[e * NPAIR + pos] = p;
}

// Phase 1: hbuf[p,h] = silu(x·w1) * (x·w3), bf16 out.
// grid (8, 44, 8): (expert, 64-wide h-tile, 128-row m-tile). block 256 (4 waves).
__global__ void h_mfma(const float* __restrict__ x,
                       const float* __restrict__ w1,
                       const float* __restrict__ w3,
                       const int* __restrict__ counts,
                       const int* __restrict__ lists,
                       ushort* __restrict__ hb) {
    const int e = blockIdx.x;
    const int cnt = counts[e];
    const int m0 = blockIdx.z * 128;
    if (m0 >= cnt) return;
    const int h0 = blockIdx.y * 64;

    __shared__ ushort sA[128 * 32];   // [m][k] k-contiguous
    __shared__ ushort sB1[64 * 32];   // [n][k]
    __shared__ ushort sB3[64 * 32];
    __shared__ int sTok[128];
    __shared__ int sPairS[128];

    const int tid = threadIdx.x;
    if (tid < 128) {
        int m = m0 + tid;
        int mc = (m < cnt) ? m : (cnt - 1);
        int p = lists[e * NPAIR + mc];
        sTok[tid] = p >> 1;                    // TOPK=2
        sPairS[tid] = (m < cnt) ? p : -1;
    }
    __syncthreads();

    const int w = tid >> 6;
    const int lane = tid & 63;
    const int l16 = lane & 15;
    const int quad = lane >> 4;

    fvec4 acc1[2][4], acc3[2][4];
    #pragma unroll
    for (int i = 0; i < 2; ++i)
        #pragma unroll
        for (int j = 0; j < 4; ++j) { acc1[i][j] = (fvec4)0.f; acc3[i][j] = (fvec4)0.f; }

    const float* w1e = w1 + (size_t)e * HDIM * DDIM + (size_t)h0 * DDIM;
    const float* w3e = w3 + (size_t)e * HDIM * DDIM + (size_t)h0 * DDIM;

    for (int k0 = 0; k0 < DDIM; k0 += 32) {
        // issue all global loads first (fp32), then convert->LDS
        fvec4 va[4], vb1[2], vb3[2];
        #pragma unroll
        for (int it = 0; it < 4; ++it) {
            int ii = tid + it * 256;            // 0..1023
            int row = ii >> 3, c4 = ii & 7;     // 128 rows x 8 float4
            va[it] = *(const fvec4*)(x + (size_t)sTok[row] * DDIM + k0 + c4 * 4);
        }
        #pragma unroll
        for (int it = 0; it < 2; ++it) {
            int ii = tid + it * 256;            // 0..511
            int row = ii >> 3, c4 = ii & 7;     // 64 rows x 8 float4
            vb1[it] = *(const fvec4*)(w1e + (size_t)row * DDIM + k0 + c4 * 4);
            vb3[it] = *(const fvec4*)(w3e + (size_t)row * DDIM + k0 + c4 * 4);
        }
        __syncthreads();   // previous iteration's compute done
        #pragma unroll
        for (int it = 0; it < 4; ++it) {
            int ii = tid + it * 256;
            int row = ii >> 3, c4 = ii & 7;
            uvec2 t = { pack2(va[it][0], va[it][1]), pack2(va[it][2], va[it][3]) };
            *(uvec2*)&sA[row * 32 + c4 * 4] = t;
        }
        #pragma unroll
        for (int it = 0; it < 2; ++it) {
            int ii = tid + it * 256;
            int row = ii >> 3, c4 = ii & 7;
            uvec2 t1 = { pack2(vb1[it][0], vb1[it][1]), pack2(vb1[it][2], vb1[it][3]) };
            uvec2 t3 = { pack2(vb3[it][0], vb3[it][1]), pack2(vb3[it][2], vb3[it][3]) };
            *(uvec2*)&sB1[row * 32 + c4 * 4] = t1;
            *(uvec2*)&sB3[row * 32 + c4 * 4] = t3;
        }
        __syncthreads();

        bf16x8 bf1[4], bf3[4];
        #pragma unroll
        for (int ni = 0; ni < 4; ++ni) {
            bf1[ni] = *(const bf16x8*)&sB1[(ni * 16 + l16) * 32 + quad * 8];
            bf3[ni] = *(const bf16x8*)&sB3[(ni * 16 + l16) * 32 + quad * 8];
        }
        #pragma unroll
        for (int mi = 0; mi < 2; ++mi) {
            bf16x8 af = *(const bf16x8*)&sA[(w * 32 + mi * 16 + l16) * 32 + quad * 8];
            #pragma unroll
            for (int ni = 0; ni < 4; ++ni) {
                acc1[mi][ni] = __builtin_amdgcn_mfma_f32_16x16x32_bf16(af, bf1[ni], acc1[mi][ni], 0, 0, 0);
                acc3[mi][ni] = __builtin_amdgcn_mfma_f32_16x16x32_bf16(af, bf3[ni], acc3[mi][ni], 0, 0, 0);
            }
        }
    }

    // epilogue: silu(h1)*h3 -> bf16 hbuf.  C/D: col=l16, row=quad*4+r
    #pragma unroll
    for (int mi = 0; mi < 2; ++mi)
        #pragma unroll
        for (int r = 0; r < 4; ++r) {
            int m = w * 32 + mi * 16 + quad * 4 + r;
            int p = sPairS[m];
            if (p >= 0) {
                size_t base = (size_t)p * HDIM + h0;
                #pragma unroll
                for (int ni = 0; ni < 4; ++ni) {
                    float a = acc1[mi][ni][r];
                    float g = acc3[mi][ni][r];
                    float s = a / (1.f + __expf(-a)) * g;
                    hb[base + ni * 16 + l16] = f2bf(s);
                }
            }
        }
}

// Phase 2: out[p,d] = hbuf[p,:] · w2[e,:,d].  M=cnt N=1024 K=2816.
// grid (8, 32, 8): (expert, 32-wide d-tile, 128-row m-tile). block 256, BK=64.
__global__ void out_mfma(const float* __restrict__ w2,
                         const int* __restrict__ counts,
                         const int* __restrict__ lists,
                         const ushort* __restrict__ hb,
                         float* __restrict__ out) {
    const int e = blockIdx.x;
    const int cnt = counts[e];
    const int m0 = blockIdx.z * 128;
    if (m0 >= cnt) return;
    const int n0 = blockIdx.y * 32;

    __shared__ ushort sA[128 * 64];   // [m][k] bf16, direct copy from hbuf
    __shared__ ushort sB[32 * 64];    // [n][k] bf16, transposed+converted from w2
    __shared__ int sPairC[128];
    __shared__ int sPairS[128];

    const int tid = threadIdx.x;
    if (tid < 128) {
        int m = m0 + tid;
        int mc = (m < cnt) ? m : (cnt - 1);
        int p = lists[e * NPAIR + mc];
        sPairC[tid] = p;
        sPairS[tid] = (m < cnt) ? p : -1;
    }
    __syncthreads();

    const int w = tid >> 6;
    const int lane = tid & 63;
    const int l16 = lane & 15;
    const int quad = lane >> 4;

    fvec4 acc[2][2];
    #pragma unroll
    for (int i = 0; i < 2; ++i) { acc[i][0] = (fvec4)0.f; acc[i][1] = (fvec4)0.f; }

    const float* w2e = w2 + (size_t)e * HDIM * DDIM + n0;
    const int kp = tid >> 3;   // 0..31 k-pair
    const int n4 = tid & 7;    // 0..7 float4 group along n

    for (int k0 = 0; k0 < HDIM; k0 += 64) {
        uvec4 va[4];
        #pragma unroll
        for (int it = 0; it < 4; ++it) {
            int ii = tid + it * 256;            // 0..1023
            int row = ii >> 3, c = ii & 7;      // 128 rows x 8 chunks of 8 bf16
            va[it] = *(const uvec4*)(hb + (size_t)sPairC[row] * HDIM + k0 + c * 8);
        }
        // w2 tile 64k x 32n fp32, transposed: thread reads k-pair, 4 n's
        fvec4 fa = *(const fvec4*)(w2e + (size_t)(k0 + kp * 2) * DDIM + n4 * 4);
        fvec4 fb = *(const fvec4*)(w2e + (size_t)(k0 + kp * 2 + 1) * DDIM + n4 * 4);
        __syncthreads();
        #pragma unroll
        for (int it = 0; it < 4; ++it) {
            int ii = tid + it * 256;
            int row = ii >> 3, c = ii & 7;
            *(uvec4*)&sA[row * 64 + c * 8] = va[it];
        }
        #pragma unroll
        for (int j = 0; j < 4; ++j) {
            int n = n4 * 4 + j;
            *(uint*)&sB[n * 64 + kp * 2] = pack2(fa[j], fb[j]);
        }
        __syncthreads();

        #pragma unroll
        for (int kk = 0; kk < 64; kk += 32) {
            bf16x8 bfr[2];
            #pragma unroll
            for (int ni = 0; ni < 2; ++ni)
                bfr[ni] = *(const bf16x8*)&sB[(ni * 16 + l16) * 64 + kk + quad * 8];
            #pragma unroll
            for (int mi = 0; mi < 2; ++mi) {
                bf16x8 af = *(const bf16x8*)&sA[(w * 32 + mi * 16 + l16) * 64 + kk + quad * 8];
                #pragma unroll
                for (int ni = 0; ni < 2; ++ni)
                    acc[mi][ni] = __builtin_amdgcn_mfma_f32_16x16x32_bf16(af, bfr[ni], acc[mi][ni], 0, 0, 0);
            }
        }
    }

    #pragma unroll
    for (int mi = 0; mi < 2; ++mi)
        #pragma unroll
        for (int r = 0; r < 4; ++r) {
            int m = w * 32 + mi * 16 + quad * 4 + r;
            int p = sPairS[m];
            if (p >= 0) {
                #pragma unroll
                for (int ni = 0; ni < 2; ++ni)
                    out[(size_t)p * DDIM + n0 + ni * 16 + l16] = acc[mi][ni][r];
            }
        }
}

extern "C" void kernel_launch(void* const* d_in, const int* in_sizes, int n_in,
                              void* d_out, int out_size, void* d_ws, size_t ws_size,
                              hipStream_t stream) {
    const float* x   = (const float*)d_in[0];
    const int*   idx = (const int*)d_in[1];
    const float* w1  = (const float*)d_in[2];
    const float* w2  = (const float*)d_in[3];
    const float* w3  = (const float*)d_in[4];
    float* out = (float*)d_out;

    char* ws = (char*)d_ws;
    int*    counts = (int*)ws;
    int*    lists  = (int*)(ws + 1024);
    ushort* hbuf   = (ushort*)(ws + 65536);

    route_kernel<<<1, NPAIR, 0, stream>>>(idx, counts, lists);
    h_mfma<<<dim3(NEXP, HDIM / 64, NPAIR / 128), 256, 0, stream>>>(
        x, w1, w3, counts, lists, hbuf);
    out_mfma<<<dim3(NEXP, DDIM / 32, NPAIR / 128), 256, 0, stream>>>(
        w2, counts, lists, hbuf, out);
}

// Round 3
// 320.349 us; speedup vs baseline: 2.5488x; 1.0155x over previous
//
#include <hip/hip_runtime.h>

// MoE SwiGLU gather, bf16 MFMA grouped GEMM. R3: padded LDS (kill 8-way
// read conflicts), register double-buffered K-loop (loads overlap MFMA),
// 8-wave blocks, phase-2 split-K x4 with atomic reduce.

#define NEXP 8
#define HDIM 2816
#define DDIM 1024
#define NPAIR 1024

typedef unsigned int uint;
typedef unsigned short ushort;
typedef __attribute__((ext_vector_type(8))) short bf16x8;
typedef __attribute__((ext_vector_type(4))) float fvec4;
typedef __attribute__((ext_vector_type(4))) uint uvec4;
typedef __attribute__((ext_vector_type(2))) uint uvec2;

__device__ __forceinline__ ushort f2bf(float f) {
    uint u = __builtin_bit_cast(uint, f);
    u += 0x7fff + ((u >> 16) & 1);          // RTNE
    return (ushort)(u >> 16);
}
__device__ __forceinline__ uint pack2(float lo, float hi) {
    return (uint)f2bf(lo) | ((uint)f2bf(hi) << 16);
}

// ws: [0] counts 32B | [1024] lists 32KB | [65536] hbuf bf16 5.77MB
__global__ __launch_bounds__(1024) void route_kernel(const int* __restrict__ idx,
                                                     int* __restrict__ counts,
                                                     int* __restrict__ lists) {
    int p = threadIdx.x;
    if (p < NEXP) counts[p] = 0;     // ws re-poisoned every call
    __syncthreads();
    int e = idx[p];
    int pos = atomicAdd(&counts[e], 1);
    lists[e * NPAIR + pos] = p;
}

// ---------------- Phase 1: hbuf[p,h] = silu(x·w1)*(x·w3) ----------------
// grid (8, 44, 8) = (expert, 64-h tile, 128-m tile), block 512 (8 waves,
// wave w owns m rows w*16..w*16+15). K-chunk 32, reg-dbuf.
#define LDA1 36   // 32 + 4 bf16 pad -> 18-dword row stride, conflict-free frags

__global__ __launch_bounds__(512) void h_mfma(const float* __restrict__ x,
                       const float* __restrict__ w1,
                       const float* __restrict__ w3,
                       const int* __restrict__ counts,
                       const int* __restrict__ lists,
                       ushort* __restrict__ hb) {
    const int e = blockIdx.x;
    const int cnt = counts[e];
    const int m0 = blockIdx.z * 128;
    if (m0 >= cnt) return;
    const int h0 = blockIdx.y * 64;

    __shared__ ushort sA[128 * LDA1];
    __shared__ ushort sB1[64 * LDA1];
    __shared__ ushort sB3[64 * LDA1];
    __shared__ int sTok[128];
    __shared__ int sPairS[128];

    const int tid = threadIdx.x;
    if (tid < 128) {
        int m = m0 + tid;
        int mc = (m < cnt) ? m : (cnt - 1);
        int p = lists[e * NPAIR + mc];
        sTok[tid] = p >> 1;                 // TOPK=2
        sPairS[tid] = (m < cnt) ? p : -1;
    }
    __syncthreads();

    const int w = tid >> 6;
    const int lane = tid & 63;
    const int l16 = lane & 15;
    const int quad = lane >> 4;

    const int arow = tid >> 3;   // 0..63 (and +64)
    const int ac4  = tid & 7;

    fvec4 acc1[4], acc3[4];
    #pragma unroll
    for (int i = 0; i < 4; ++i) { acc1[i] = (fvec4)0.f; acc3[i] = (fvec4)0.f; }

    const float* w1e = w1 + (size_t)e * HDIM * DDIM + (size_t)h0 * DDIM;
    const float* w3e = w3 + (size_t)e * HDIM * DDIM + (size_t)h0 * DDIM;
    const float* xr0 = x + (size_t)sTok[arow] * DDIM + ac4 * 4;
    const float* xr1 = x + (size_t)sTok[arow + 64] * DDIM + ac4 * 4;
    const float* wr1 = w1e + (size_t)arow * DDIM + ac4 * 4;
    const float* wr3 = w3e + (size_t)arow * DDIM + ac4 * 4;

    fvec4 va0, va1, vb1, vb3;
    va0 = *(const fvec4*)(xr0);
    va1 = *(const fvec4*)(xr1);
    vb1 = *(const fvec4*)(wr1);
    vb3 = *(const fvec4*)(wr3);

    for (int k0 = 0; k0 < DDIM; k0 += 32) {
        __syncthreads();   // all waves done reading previous chunk's LDS
        {
            uvec2 t;
            t = (uvec2){ pack2(va0[0], va0[1]), pack2(va0[2], va0[3]) };
            *(uvec2*)&sA[arow * LDA1 + ac4 * 4] = t;
            t = (uvec2){ pack2(va1[0], va1[1]), pack2(va1[2], va1[3]) };
            *(uvec2*)&sA[(arow + 64) * LDA1 + ac4 * 4] = t;
            t = (uvec2){ pack2(vb1[0], vb1[1]), pack2(vb1[2], vb1[3]) };
            *(uvec2*)&sB1[arow * LDA1 + ac4 * 4] = t;
            t = (uvec2){ pack2(vb3[0], vb3[1]), pack2(vb3[2], vb3[3]) };
            *(uvec2*)&sB3[arow * LDA1 + ac4 * 4] = t;
        }
        __syncthreads();

        // prefetch next chunk while MFMA runs (clamped: last iter reloads)
        int kn = (k0 + 32 < DDIM) ? (k0 + 32) : k0;
        va0 = *(const fvec4*)(xr0 + kn);
        va1 = *(const fvec4*)(xr1 + kn);
        vb1 = *(const fvec4*)(wr1 + kn);
        vb3 = *(const fvec4*)(wr3 + kn);

        bf16x8 af = *(const bf16x8*)&sA[(w * 16 + l16) * LDA1 + quad * 8];
        #pragma unroll
        for (int ni = 0; ni < 4; ++ni) {
            bf16x8 b1 = *(const bf16x8*)&sB1[(ni * 16 + l16) * LDA1 + quad * 8];
            bf16x8 b3 = *(const bf16x8*)&sB3[(ni * 16 + l16) * LDA1 + quad * 8];
            acc1[ni] = __builtin_amdgcn_mfma_f32_16x16x32_bf16(af, b1, acc1[ni], 0, 0, 0);
            acc3[ni] = __builtin_amdgcn_mfma_f32_16x16x32_bf16(af, b3, acc3[ni], 0, 0, 0);
        }
    }

    // epilogue: C/D layout col=l16, row=quad*4+r
    #pragma unroll
    for (int r = 0; r < 4; ++r) {
        int m = w * 16 + quad * 4 + r;
        int p = sPairS[m];
        if (p >= 0) {
            size_t base = (size_t)p * HDIM + h0;
            #pragma unroll
            for (int ni = 0; ni < 4; ++ni) {
                float a = acc1[ni][r];
                float g = acc3[ni][r];
                float s = a / (1.f + __expf(-a)) * g;
                hb[base + ni * 16 + l16] = f2bf(s);
            }
        }
    }
}

// ---------------- Phase 2: out[p,d] += hbuf[p,:]·w2[e,:,d] ----------------
// grid (8, 16, 32): (expert, 64-d tile, mblock*4 + splitK). block 512.
// K-chunk 64, split-K over 4x704, fp32 atomicAdd into zeroed out.
#define LDA2 68   // 64 + 4 bf16 pad

__global__ __launch_bounds__(512) void out_mfma(const float* __restrict__ w2,
                         const int* __restrict__ counts,
                         const int* __restrict__ lists,
                         const ushort* __restrict__ hb,
                         float* __restrict__ out) {
    const int e = blockIdx.x;
    const int cnt = counts[e];
    const int mb = blockIdx.z >> 2;
    const int sk = blockIdx.z & 3;
    const int m0 = mb * 128;
    if (m0 >= cnt) return;
    const int n0 = blockIdx.y * 64;
    const int kbase = sk * (HDIM / 4);      // 704 per split, 11 chunks of 64

    __shared__ ushort sA[128 * LDA2];
    __shared__ ushort sB[64 * LDA2];
    __shared__ int sPairC[128];
    __shared__ int sPairS[128];

    const int tid = threadIdx.x;
    if (tid < 128) {
        int m = m0 + tid;
        int mc = (m < cnt) ? m : (cnt - 1);
        int p = lists[e * NPAIR + mc];
        sPairC[tid] = p;
        sPairS[tid] = (m < cnt) ? p : -1;
    }
    __syncthreads();

    const int w = tid >> 6;
    const int lane = tid & 63;
    const int l16 = lane & 15;
    const int quad = lane >> 4;

    const int arow = tid >> 3;    // 0..63 (and +64), 8 x 16B chunks per row
    const int ac   = tid & 7;
    const int kp   = tid >> 4;    // 0..31 k-pair
    const int n4   = tid & 15;    // 0..15 float4 group along n

    fvec4 acc[4];
    #pragma unroll
    for (int i = 0; i < 4; ++i) acc[i] = (fvec4)0.f;

    const float* w2e = w2 + (size_t)e * HDIM * DDIM + n0;
    const ushort* ha0 = hb + (size_t)sPairC[arow] * HDIM + ac * 8;
    const ushort* ha1 = hb + (size_t)sPairC[arow + 64] * HDIM + ac * 8;
    const float* wk0 = w2e + (size_t)(kbase + 2 * kp) * DDIM + n4 * 4;

    uvec4 va0, va1;
    fvec4 fa, fb;
    va0 = *(const uvec4*)(ha0 + kbase);
    va1 = *(const uvec4*)(ha1 + kbase);
    fa = *(const fvec4*)(wk0);
    fb = *(const fvec4*)(wk0 + DDIM);

    const int NCH = (HDIM / 4) / 64;   // 11
    for (int kc = 0; kc < NCH; ++kc) {
        __syncthreads();
        *(uvec4*)&sA[arow * LDA2 + ac * 8] = va0;
        *(uvec4*)&sA[(arow + 64) * LDA2 + ac * 8] = va1;
        #pragma unroll
        for (int j = 0; j < 4; ++j)
            *(uint*)&sB[(n4 * 4 + j) * LDA2 + kp * 2] = pack2(fa[j], fb[j]);
        __syncthreads();

        int kcn = (kc + 1 < NCH) ? (kc + 1) : kc;
        int koff = kcn * 64;
        va0 = *(const uvec4*)(ha0 + kbase + koff);
        va1 = *(const uvec4*)(ha1 + kbase + koff);
        fa = *(const fvec4*)(wk0 + (size_t)koff * DDIM);
        fb = *(const fvec4*)(wk0 + (size_t)(koff + 1) * DDIM);

        #pragma unroll
        for (int kk = 0; kk < 64; kk += 32) {
            bf16x8 af = *(const bf16x8*)&sA[(w * 16 + l16) * LDA2 + kk + quad * 8];
            #pragma unroll
            for (int ni = 0; ni < 4; ++ni) {
                bf16x8 bf = *(const bf16x8*)&sB[(ni * 16 + l16) * LDA2 + kk + quad * 8];
                acc[ni] = __builtin_amdgcn_mfma_f32_16x16x32_bf16(af, bf, acc[ni], 0, 0, 0);
            }
        }
    }

    #pragma unroll
    for (int r = 0; r < 4; ++r) {
        int m = w * 16 + quad * 4 + r;
        int p = sPairS[m];
        if (p >= 0) {
            #pragma unroll
            for (int ni = 0; ni < 4; ++ni)
                atomicAdd(&out[(size_t)p * DDIM + n0 + ni * 16 + l16], acc[ni][r]);
        }
    }
}

extern "C" void kernel_launch(void* const* d_in, const int* in_sizes, int n_in,
                              void* d_out, int out_size, void* d_ws, size_t ws_size,
                              hipStream_t stream) {
    const float* x   = (const float*)d_in[0];
    const int*   idx = (const int*)d_in[1];
    const float* w1  = (const float*)d_in[2];
    const float* w2  = (const float*)d_in[3];
    const float* w3  = (const float*)d_in[4];
    float* out = (float*)d_out;

    char* ws = (char*)d_ws;
    int*    counts = (int*)ws;
    int*    lists  = (int*)(ws + 1024);
    ushort* hbuf   = (ushort*)(ws + 65536);

    hipMemsetAsync(out, 0, (size_t)out_size * sizeof(float), stream);
    route_kernel<<<1, NPAIR, 0, stream>>>(idx, counts, lists);
    h_mfma<<<dim3(NEXP, HDIM / 64, NPAIR / 128), 512, 0, stream>>>(
        x, w1, w3, counts, lists, hbuf);
    out_mfma<<<dim3(NEXP, DDIM / 64, (NPAIR / 128) * 4), 512, 0, stream>>>(
        w2, counts, lists, hbuf, out);
}